// Round 5
// baseline (181.743 us; speedup 1.0000x reference)
//
#include <hip/hip_runtime.h>
#include <hip/hip_bf16.h>

// SelfAttention: B=4, S=4096, Din=768, Dout=64.
// R5 = R4 (swapped QK^T, lane-local softmax, exp2 domain, defer-max, QBLK=32)
//      + ordering fixed structurally:
//      * P tile double-buffered by iteration parity (2x2KB in o_lds slice)
//        -> WAR across iterations gone, no end-of-loop fence, loads hoistable
//      * one lgkmcnt(0)+memory fence between P-write and P-read (RAW)
//      * fence before epilogue publish (float stores overwrite P region)
//      * V fragments loaded before softmax (latency hidden under softmax+fence)

typedef __attribute__((ext_vector_type(8))) __bf16 bf16x8;
typedef __attribute__((ext_vector_type(4))) __bf16 bf16x4;
typedef __attribute__((ext_vector_type(4))) float  f32x4;

constexpr int BATCH = 4;
constexpr int SEQ   = 4096;
constexpr int DIN   = 768;
constexpr int NTOT  = 192;          // 3 * 64 packed output features
constexpr int MROWS = BATCH * SEQ;  // 16384

__device__ __forceinline__ f32x4 mfma16(bf16x8 a, bf16x8 b, f32x4 c) {
    return __builtin_amdgcn_mfma_f32_16x16x32_bf16(a, b, c, 0, 0, 0);
}

// ---------------- k0: pack Wq|Wk|Wv -> bf16 [192][768]; Wq pre-scaled by
// 0.125*log2(e) so attention scores come out in exp2 domain.
__global__ __launch_bounds__(256) void convert_w(
        const float* __restrict__ Wq, const float* __restrict__ Wk,
        const float* __restrict__ Wv, __bf16* __restrict__ wb) {
    int i = blockIdx.x * 256 + threadIdx.x;
    if (i >= NTOT * DIN) return;
    int n = i / DIN;
    const float* src = (n < 64) ? Wq : (n < 128) ? Wk : Wv;
    float scale = (n < 64) ? 0.125f * 1.44269504f : 1.0f;
    wb[i] = (__bf16)(src[(n & 63) * DIN + (i % DIN)] * scale);
}

// ---------------- k1: q,k,v = x @ W^T   (M=16384, N=192, K=768)
// grid = 1024 blocks of 16 rows; 4 waves/block, each wave 3 n-tiles.
__global__ __launch_bounds__(256) void qkv_proj(
        const float* __restrict__ x, const __bf16* __restrict__ wb,
        __bf16* __restrict__ q, __bf16* __restrict__ k, __bf16* __restrict__ vT) {
    const int wave = threadIdx.x >> 6, lane = threadIdx.x & 63;
    const int lr = lane & 15;
    const int g  = lane >> 4;
    const int lk = g * 8;
    const int row = blockIdx.x * 16 + lr;

    f32x4 acc[3];
#pragma unroll
    for (int t = 0; t < 3; ++t) acc[t] = f32x4{0.f, 0.f, 0.f, 0.f};

    for (int k0 = 0; k0 < DIN; k0 += 32) {
        const float* xp = x + (size_t)row * DIN + k0 + lk;
        float4 xa = *(const float4*)(xp);
        float4 xb = *(const float4*)(xp + 4);
        bf16x8 af;
        af[0] = (__bf16)xa.x; af[1] = (__bf16)xa.y; af[2] = (__bf16)xa.z; af[3] = (__bf16)xa.w;
        af[4] = (__bf16)xb.x; af[5] = (__bf16)xb.y; af[6] = (__bf16)xb.z; af[7] = (__bf16)xb.w;
#pragma unroll
        for (int t = 0; t < 3; ++t) {
            int nt = wave * 3 + t;
            bf16x8 bf = *(const bf16x8*)(wb + (size_t)(nt * 16 + lr) * DIN + k0 + lk);
            acc[t] = mfma16(af, bf, acc[t]);
        }
    }

    const int orow = blockIdx.x * 16 + g * 4;
#pragma unroll
    for (int t = 0; t < 3; ++t) {
        int n = (wave * 3 + t) * 16 + lr;
#pragma unroll
        for (int r = 0; r < 4; ++r) {
            int m = orow + r;
            __bf16 hv = (__bf16)acc[t][r];
            if (n < 64) {
                q[(size_t)m * 64 + n] = hv;
            } else if (n < 128) {
                k[(size_t)m * 64 + (n - 64)] = hv;
            } else {
                int b = m >> 12, s = m & (SEQ - 1);
                vT[(size_t)b * 64 * SEQ + (size_t)(n - 128) * SEQ + s] = hv;
            }
        }
    }
}

// ---------------- k2: flash attention, swapped-operand QK^T.
// grid = (SEQ/32, BATCH), block = 512 (8 waves = 2 q-strips x 4 kv-quarters).
// Wave: 16 q-rows, 1024 kv positions (16 iters of KVT=64).
// Lane holds S[kv=j*16+g*4+r][q=lr] -> softmax row is lane-local.
__global__ __launch_bounds__(512, 4) void attn(
        const __bf16* __restrict__ q, const __bf16* __restrict__ k,
        const __bf16* __restrict__ vT, float* __restrict__ out) {
    const int tid  = threadIdx.x;
    const int wave = tid >> 6, lane = tid & 63;
    const int strip = wave >> 2, kvq = wave & 3;
    const int b  = blockIdx.y;
    const int q0 = blockIdx.x * 32 + strip * 16;
    const int lr = lane & 15;
    const int g  = lane >> 4;
    const int lk = g * 8;

    const __bf16* qp = q  + (size_t)b * SEQ * 64;
    const __bf16* kp = k  + (size_t)b * SEQ * 64;
    const __bf16* vp = vT + (size_t)b * 64 * SEQ;

    __shared__ __align__(16) float o_lds[8][16][64];   // 32 KiB merge scratch
    __shared__ float m_lds[8][16];
    __shared__ float l_lds[8][16];
    // per-wave P tile: double-buffered 2 x (16 rows x 128 B) inside own o region
    char* pw = (char*)&o_lds[wave][0][0];

    bf16x8 qf0 = *(const bf16x8*)(qp + (size_t)(q0 + lr) * 64 + lk);
    bf16x8 qf1 = *(const bf16x8*)(qp + (size_t)(q0 + lr) * 64 + 32 + lk);

    f32x4 acc_o[4];
#pragma unroll
    for (int t = 0; t < 4; ++t) acc_o[t] = f32x4{0.f, 0.f, 0.f, 0.f};
    float m_run = -1e30f, l_run = 0.f;

    const int rx = (lr & 7) << 4;      // swizzle: byte = (2*kv) ^ rx, row = lr

    const int kv_lo = kvq * (SEQ / 4);
    for (int it = 0; it < (SEQ / 4) / 64; ++it) {
        const int kv0 = kv_lo + it * 64;
        char* pb = pw + ((it & 1) << 11);   // parity buffer (2 KiB each)

        // ---- S^T = K Q^T : s[j][r] = S[kv0+j*16+g*4+r][q0+lr] (exp2 domain)
        f32x4 s[4];
#pragma unroll
        for (int j = 0; j < 4; ++j) {
            const __bf16* kr = kp + (size_t)(kv0 + j * 16 + lr) * 64 + lk;
            bf16x8 kf0 = *(const bf16x8*)(kr);
            bf16x8 kf1 = *(const bf16x8*)(kr + 32);
            f32x4 a = f32x4{0.f, 0.f, 0.f, 0.f};
            a = mfma16(kf0, qf0, a);
            a = mfma16(kf1, qf1, a);
            s[j] = a;
        }

        // ---- V fragments issued early: latency hides under softmax + fence
        bf16x8 vf[8];
#pragma unroll
        for (int ks = 0; ks < 2; ++ks)
#pragma unroll
            for (int t = 0; t < 4; ++t)
                vf[ks * 4 + t] = *(const bf16x8*)(vp + (size_t)(t * 16 + lr) * SEQ +
                                                  kv0 + ks * 32 + lk);

        // ---- row max: 15 in-reg fmax + 2 shuffles (lanes lr,+16,+32,+48)
        float pm = s[0][0];
#pragma unroll
        for (int j = 0; j < 4; ++j)
#pragma unroll
            for (int r = 0; r < 4; ++r) pm = fmaxf(pm, s[j][r]);
        pm = fmaxf(pm, __shfl_xor(pm, 16));
        pm = fmaxf(pm, __shfl_xor(pm, 32));

        // ---- defer-max: only rescale when max grew by > 8 (exp2 units)
        if (!__all(pm <= m_run + 8.0f)) {
            float mn = fmaxf(m_run, pm);
            float al = exp2f(m_run - mn);
            l_run *= al;
#pragma unroll
            for (int t = 0; t < 4; ++t)
#pragma unroll
                for (int r = 0; r < 4; ++r) acc_o[t][r] *= al;
            m_run = mn;
        }

        // ---- p = exp2(s - m); partial l (cross-lane sum deferred); pack to LDS
#pragma unroll
        for (int j = 0; j < 4; ++j) {
            bf16x4 pbv;
#pragma unroll
            for (int r = 0; r < 4; ++r) {
                float p = exp2f(s[j][r] - m_run);
                l_run += p;
                pbv[r] = (__bf16)p;
            }
            *(bf16x4*)(pb + lr * 128 + ((j * 32 + g * 8) ^ rx)) = pbv;
        }
        // RAW fence: P writes complete (HW) and stay above reads (compiler)
        asm volatile("s_waitcnt lgkmcnt(0)" ::: "memory");

        // ---- O^T += V^T P : acc_o[t][r] = O[d=t*16+g*4+r][q=lr]
#pragma unroll
        for (int ks = 0; ks < 2; ++ks) {
            bf16x8 pf = *(const bf16x8*)(pb + lr * 128 + ((ks * 64 + g * 16) ^ rx));
#pragma unroll
            for (int t = 0; t < 4; ++t)
                acc_o[t] = mfma16(vf[ks * 4 + t], pf, acc_o[t]);
        }
    }

    // ---- finish deferred l reduction; publish partials (overwrites P region)
    l_run += __shfl_xor(l_run, 16);
    l_run += __shfl_xor(l_run, 32);
    asm volatile("s_waitcnt lgkmcnt(0)" ::: "memory");
#pragma unroll
    for (int t = 0; t < 4; ++t)
#pragma unroll
        for (int r = 0; r < 4; ++r)
            o_lds[wave][lr][t * 16 + g * 4 + r] = acc_o[t][r];
    if (lane < 16) {
        m_lds[wave][lr] = m_run;
        l_lds[wave][lr] = l_run;
    }
    __syncthreads();

    // ---- merge 4 kv-quarters per strip
    if (tid < 32) {
        int row = tid & 15, st = tid >> 4;
        float M = -1e30f;
#pragma unroll
        for (int w = 0; w < 4; ++w) M = fmaxf(M, m_lds[st * 4 + w][row]);
        float L = 0.f;
#pragma unroll
        for (int w = 0; w < 4; ++w) {
            float sc = exp2f(m_lds[st * 4 + w][row] - M);
            m_lds[st * 4 + w][row] = sc;
            L += l_lds[st * 4 + w][row] * sc;
        }
        l_lds[st * 4][row] = 1.f / L;
    }
    __syncthreads();

    // ---- out[row][col] = sum_w o_w[col][row]*sc_w / L   (2048 elems, 4/thread)
    float* ob = out + ((size_t)b * SEQ + blockIdx.x * 32) * 64;
#pragma unroll
    for (int e = 0; e < 4; ++e) {
        int idx = tid + e * 512;
        int row = idx >> 6, col = idx & 63;     // row 0..31 within block
        int st = row >> 4, ri = row & 15;
        float a = 0.f;
#pragma unroll
        for (int w = 0; w < 4; ++w)
            a += o_lds[st * 4 + w][ri][col] * m_lds[st * 4 + w][ri];
        ob[(size_t)row * 64 + col] = a * l_lds[st * 4][ri];
    }
}

extern "C" void kernel_launch(void* const* d_in, const int* in_sizes, int n_in,
                              void* d_out, int out_size, void* d_ws, size_t ws_size,
                              hipStream_t stream) {
    const float* x  = (const float*)d_in[0];
    const float* Wq = (const float*)d_in[1];
    const float* Wk = (const float*)d_in[2];
    const float* Wv = (const float*)d_in[3];
    float* out = (float*)d_out;

    char* ws = (char*)d_ws;
    __bf16* wb = (__bf16*)(ws);
    __bf16* qb = (__bf16*)(ws + 294912);
    __bf16* kb = (__bf16*)(ws + 294912 + 2097152);
    __bf16* vT = (__bf16*)(ws + 294912 + 2u * 2097152);

    convert_w<<<dim3((NTOT * DIN + 255) / 256), dim3(256), 0, stream>>>(Wq, Wk, Wv, wb);
    qkv_proj<<<dim3(MROWS / 16), dim3(256), 0, stream>>>(x, wb, qb, kb, vT);
    attn<<<dim3(SEQ / 32, BATCH), dim3(512), 0, stream>>>(qb, kb, vT, out);
}